// Round 11
// baseline (253.134 us; speedup 1.0000x reference)
//
#include <hip/hip_runtime.h>
#include <stdint.h>
#include <stddef.h>

#define S_LEN 4096
#define NHEAD 16
#define HDIM 64
#define DMODEL 1024
#define NBATCH 2
#define LOG2E 1.4426950408889634f

typedef __attribute__((ext_vector_type(8))) short bf16x8;
typedef __attribute__((ext_vector_type(4))) float f32x4;
typedef __attribute__((ext_vector_type(16))) float f32x16;
typedef __attribute__((ext_vector_type(2))) unsigned int uint2v;
typedef __attribute__((ext_vector_type(4))) unsigned int uint4v;

__device__ inline unsigned short f2b(float f) {
    union { float f; unsigned int u; } x; x.f = f;
    unsigned int r = (x.u + 0x7fffu + ((x.u >> 16) & 1u)) >> 16;
    return (unsigned short)r;
}

__device__ inline unsigned cvt_pk_bf16(float lo, float hi) {
    unsigned r;
    asm("v_cvt_pk_bf16_f32 %0, %1, %2" : "=v"(r) : "v"(lo), "v"(hi));
    return r;
}

__device__ inline float exp_fast(float x) {  // 2^x, single v_exp_f32 (pre-scaled by log2e)
    float r;
    asm("v_exp_f32 %0, %1" : "=v"(r) : "v"(x));
    return r;
}

__device__ inline void gload_lds16(const void* g, void* l) {
    __builtin_amdgcn_global_load_lds((const __attribute__((address_space(1))) void*)g,
                                     (__attribute__((address_space(3))) void*)l,
                                     16, 0, 0);
}

// ---------------- fp32 -> bf16 converts ----------------
__global__ void cvt_x(const float* __restrict__ in, unsigned short* __restrict__ out, int n4) {
    int i = blockIdx.x * 256 + threadIdx.x;
    if (i >= n4) return;
    float4 v = ((const float4*)in)[i];
    ushort4 o;
    o.x = f2b(v.x); o.y = f2b(v.y); o.z = f2b(v.z); o.w = f2b(v.w);
    ((ushort4*)out)[i] = o;
}

__global__ void cvt_w(const float* __restrict__ w0, const float* __restrict__ w1,
                      const float* __restrict__ w2, const float* __restrict__ w3,
                      unsigned short* __restrict__ dst) {
    int z = blockIdx.y;
    const float* src = (z == 0) ? w0 : (z == 1) ? w1 : (z == 2) ? w2 : w3;
    int i = blockIdx.x * 256 + threadIdx.x;
    float4 v = ((const float4*)src)[i];
    ushort4 o;
    o.x = f2b(v.x); o.y = f2b(v.y); o.z = f2b(v.z); o.w = f2b(v.w);
    ((ushort4*)(dst + (size_t)z * DMODEL * DMODEL))[i] = o;
}

// ---------------- fused QKV projection ----------------
__global__ __launch_bounds__(256, 2)
void gemm_qkv(const unsigned short* __restrict__ xb,
              const unsigned short* __restrict__ wqb,
              const unsigned short* __restrict__ wkb,
              const unsigned short* __restrict__ wvb,
              unsigned short* __restrict__ Qb,
              unsigned short* __restrict__ Kb,
              unsigned short* __restrict__ Vt,
              float qscale) {
    __shared__ unsigned short Asl[128 * 64];
    __shared__ unsigned short Bsl[128 * 64];
    const int tid  = threadIdx.x;
    const int lane = tid & 63;
    const int wid  = tid >> 6;
    const int wm   = (wid >> 1) * 64, wn = (wid & 1) * 64;
    const int lr   = lane & 15, lk = lane >> 4;
    const int z    = blockIdx.z;

    const unsigned short* A;
    const unsigned short* Bw;
    int m0, n0;
    if (z < 2) { A = xb; Bw = z ? wkb : wqb; m0 = blockIdx.x * 128; n0 = blockIdx.y * 128; }
    else       { A = wvb; Bw = xb;           m0 = blockIdx.y * 128; n0 = blockIdx.x * 128; }

    f32x4 acc[4][4];
#pragma unroll
    for (int i = 0; i < 4; ++i)
#pragma unroll
        for (int j = 0; j < 4; ++j) acc[i][j] = (f32x4){0.f, 0.f, 0.f, 0.f};

    for (int kt = 0; kt < DMODEL; kt += 64) {
#pragma unroll
        for (int i = 0; i < 4; ++i) {
            int c = i * 256 + tid;
            int r = c >> 3, gc = (c & 7) ^ (r & 7);
            gload_lds16(A + (size_t)(m0 + r) * DMODEL + kt + gc * 8, Asl + c * 8);
        }
#pragma unroll
        for (int i = 0; i < 4; ++i) {
            int c = i * 256 + tid;
            int r = c >> 3, gc = (c & 7) ^ (r & 7);
            gload_lds16(Bw + (size_t)(n0 + r) * DMODEL + kt + gc * 8, Bsl + c * 8);
        }
        __syncthreads();
#pragma unroll
        for (int kh = 0; kh < 2; ++kh) {
            int cl = kh * 4 + lk;
            bf16x8 af[4], bfr[4];
#pragma unroll
            for (int m = 0; m < 4; ++m) {
                int r = wm + m * 16 + lr;
                af[m] = *(const bf16x8*)(Asl + r * 64 + ((cl ^ (r & 7)) * 8));
            }
#pragma unroll
            for (int n = 0; n < 4; ++n) {
                int r = wn + n * 16 + lr;
                bfr[n] = *(const bf16x8*)(Bsl + r * 64 + ((cl ^ (r & 7)) * 8));
            }
#pragma unroll
            for (int m = 0; m < 4; ++m)
#pragma unroll
                for (int n = 0; n < 4; ++n)
                    acc[m][n] = __builtin_amdgcn_mfma_f32_16x16x32_bf16(af[m], bfr[n], acc[m][n], 0, 0, 0);
        }
        __syncthreads();
    }

#pragma unroll
    for (int m = 0; m < 4; ++m) {
#pragma unroll
        for (int n = 0; n < 4; ++n) {
            int gn = n0 + wn + n * 16 + lr;
#pragma unroll
            for (int r = 0; r < 4; ++r) {
                int gm = m0 + wm + m * 16 + lk * 4 + r;
                float v = acc[m][n][r];
                if (z == 0) {
                    int b = gm >> 12, s = gm & 4095, h = gn >> 6, hd = gn & 63;
                    Qb[((size_t)((b * NHEAD + h) * S_LEN + s)) * HDIM + hd] = f2b(v * qscale);
                } else if (z == 1) {
                    int b = gm >> 12, s = gm & 4095, h = gn >> 6, hd = gn & 63;
                    Kb[((size_t)((b * NHEAD + h) * S_LEN + s)) * HDIM + hd] = f2b(v);
                } else {
                    int h = gm >> 6, hd = gm & 63, b = gn >> 12, s = gn & 4095;
                    Vt[((size_t)((b * NHEAD + h) * HDIM + hd)) * S_LEN + s] = f2b(v);
                }
            }
        }
    }
}

// ---------------- output projection: fp32 out + bias ----------------
__global__ __launch_bounds__(256, 2)
void gemm_out(const unsigned short* __restrict__ A,
              const unsigned short* __restrict__ Bw,
              float* __restrict__ out, const float* __restrict__ bias) {
    __shared__ unsigned short Asl[128 * 64];
    __shared__ unsigned short Bsl[128 * 64];
    const int tid  = threadIdx.x;
    const int lane = tid & 63;
    const int wid  = tid >> 6;
    const int wm   = (wid >> 1) * 64, wn = (wid & 1) * 64;
    const int lr   = lane & 15, lk = lane >> 4;
    const int m0   = blockIdx.x * 128, n0 = blockIdx.y * 128;

    f32x4 acc[4][4];
#pragma unroll
    for (int i = 0; i < 4; ++i)
#pragma unroll
        for (int j = 0; j < 4; ++j) acc[i][j] = (f32x4){0.f, 0.f, 0.f, 0.f};

    for (int kt = 0; kt < DMODEL; kt += 64) {
#pragma unroll
        for (int i = 0; i < 4; ++i) {
            int c = i * 256 + tid;
            int r = c >> 3, gc = (c & 7) ^ (r & 7);
            gload_lds16(A + (size_t)(m0 + r) * DMODEL + kt + gc * 8, Asl + c * 8);
        }
#pragma unroll
        for (int i = 0; i < 4; ++i) {
            int c = i * 256 + tid;
            int r = c >> 3, gc = (c & 7) ^ (r & 7);
            gload_lds16(Bw + (size_t)(n0 + r) * DMODEL + kt + gc * 8, Bsl + c * 8);
        }
        __syncthreads();
#pragma unroll
        for (int kh = 0; kh < 2; ++kh) {
            int cl = kh * 4 + lk;
            bf16x8 af[4], bfr[4];
#pragma unroll
            for (int m = 0; m < 4; ++m) {
                int r = wm + m * 16 + lr;
                af[m] = *(const bf16x8*)(Asl + r * 64 + ((cl ^ (r & 7)) * 8));
            }
#pragma unroll
            for (int n = 0; n < 4; ++n) {
                int r = wn + n * 16 + lr;
                bfr[n] = *(const bf16x8*)(Bsl + r * 64 + ((cl ^ (r & 7)) * 8));
            }
#pragma unroll
            for (int m = 0; m < 4; ++m)
#pragma unroll
                for (int n = 0; n < 4; ++n)
                    acc[m][n] = __builtin_amdgcn_mfma_f32_16x16x32_bf16(af[m], bfr[n], acc[m][n], 0, 0, 0);
        }
        __syncthreads();
    }
#pragma unroll
    for (int m = 0; m < 4; ++m)
#pragma unroll
        for (int n = 0; n < 4; ++n) {
            int gn = n0 + wn + n * 16 + lr;
#pragma unroll
            for (int r = 0; r < 4; ++r) {
                int gm = m0 + wm + m * 16 + lk * 4 + r;
                out[(size_t)gm * DMODEL + gn] = acc[m][n][r] + bias[gn];
            }
        }
}

// ---------------- flash attention (causal): K direct from L2 to registers -------
// V staged in LDS (coalesced HBM->LDS); K fragments loaded per-wave from global
// (L2-resident via XCD head grouping) with one-tile register prefetch (kfA/kfB).
// Halves LDS read pressure (8 of 16 ds_read_b128/tile removed) and staging gloads.
__global__ __launch_bounds__(256)
void attn_fwd(const unsigned short* __restrict__ Q,
              const unsigned short* __restrict__ K,
              const unsigned short* __restrict__ Vt,
              unsigned short* __restrict__ ctx) {
    __shared__ unsigned short Vl[2][4096];

    const int tid  = threadIdx.x;
    const int lane = tid & 63;
    const int w    = tid >> 6;
    const int l31  = lane & 31;
    const int hi   = lane >> 5;

    // balanced mapping (r10): xcd = bid&7, cu = (bid>>3)&31, slot = bid>>8, u = cu>>2
    const int bid  = blockIdx.x;
    const int xcd  = bid & 7;
    const int cu   = (bid >> 3) & 31;
    const int slot = bid >> 8;
    const int u    = cu >> 2;
    int qt;
    if      (slot == 0) qt = 31 - u;
    else if (slot == 1) qt = 16 + u;
    else if (slot == 2) qt = 15 - u;
    else                qt = u;
    const int bh   = (xcd << 2) | (cu & 3);          // 4 heads per XCD (L2 locality)
    const int b    = bh >> 4, h = bh & 15;
    const int q0   = qt * 128;
    const int qw0  = q0 + w * 32;

    const unsigned short* Qh = Q  + (size_t)bh * S_LEN * HDIM;
    const unsigned short* Kh = K  + (size_t)bh * S_LEN * HDIM;
    const unsigned short* Vh = Vt + (size_t)bh * HDIM * S_LEN;

    // V staging source (fragment-order): slice sk = tid>>6 covers V^T rows (sk>>1)*32+l31,
    // kv chunk (sk&1)*16 + hiS*8 .. +8 -- per 64-kv tile, 2 gload_lds per thread.
    const int sk   = tid >> 6;
    const int lS31 = tid & 31, hiS = (tid >> 5) & 1;
    const unsigned short* vb0 = Vh + (size_t)lS31 * S_LEN + sk * 16 + hiS * 8;
    const unsigned short* vb1 = Vh + (size_t)(32 + lS31) * S_LEN + sk * 16 + hiS * 8;

    // K direct-load base: lane l reads K[kv0 + (l&31)][s*16 + (l>>5)*8 .. +8]
    const unsigned short* krow = Kh + (size_t)l31 * HDIM + hi * 8;

    // Q fragments (B-operand): col q = lane&31, k-elems hd = s*16 + hi*8 + 0..7
    bf16x8 qf[4];
    {
        const unsigned short* qrow = Qh + (size_t)(qw0 + l31) * HDIM + hi * 8;
#pragma unroll
        for (int s = 0; s < 4; ++s) qf[s] = *(const bf16x8*)(qrow + s * 16);
    }

    bf16x8 ones;
#pragma unroll
    for (int j = 0; j < 8; ++j) ones[j] = (short)0x3F80;

    f32x16 z16;
#pragma unroll
    for (int j = 0; j < 16; ++j) z16[j] = 0.f;

    const unsigned short* VL = &Vl[0][0] + lane * 8;

    f32x16 o0, o1, ls;
#pragma unroll
    for (int j = 0; j < 16; ++j) { o0[j] = 0.f; o1[j] = 0.f; ls[j] = 0.f; }

    const int nt = 2 * qt + 2;             // always even

    auto stage = [&](int buf, int kv0) {
        gload_lds16(vb0 + kv0, &Vl[buf][(size_t)tid * 8]);
        gload_lds16(vb1 + kv0, &Vl[buf][2048 + (size_t)tid * 8]);
    };

    auto loadK = [&](int kv0, bf16x8* kf) {
        const unsigned short* kr = krow + (size_t)kv0 * HDIM;
#pragma unroll
        for (int s = 0; s < 4; ++s) {
            kf[s]     = *(const bf16x8*)(kr + s * 16);
            kf[4 + s] = *(const bf16x8*)(kr + 32 * HDIM + s * 16);
        }
    };

    auto packfrag = [&](const f32x16& v, int base) -> bf16x8 {
        unsigned a0 = cvt_pk_bf16(v[base + 0], v[base + 1]), a1 = cvt_pk_bf16(v[base + 2], v[base + 3]);
        unsigned b0 = cvt_pk_bf16(v[base + 4], v[base + 5]), b1 = cvt_pk_bf16(v[base + 6], v[base + 7]);
        uint2v r0 = __builtin_amdgcn_permlane32_swap(a0, b0, false, false);
        uint2v r1 = __builtin_amdgcn_permlane32_swap(a1, b1, false, false);
        uint4v f; f.x = r0.x; f.y = r1.x; f.z = r0.y; f.w = r1.y;
        return __builtin_bit_cast(bf16x8, f);
    };

    auto compute = [&](int buf, int kv0, const bf16x8* kf) {
        const unsigned short* VB = VL + buf * 4096;
        const int q = qw0 + l31;

        // ---- half 0: kv rows [kv0, kv0+32) ----
        if (kv0 < qw0 + 32) {
            __builtin_amdgcn_s_setprio(1);
            f32x16 st = __builtin_amdgcn_mfma_f32_32x32x16_bf16(kf[0], qf[0], z16, 0, 0, 0);
#pragma unroll
            for (int s = 1; s < 4; ++s)
                st = __builtin_amdgcn_mfma_f32_32x32x16_bf16(kf[s], qf[s], st, 0, 0, 0);
            __builtin_amdgcn_s_setprio(0);
            if (kv0 + 31 > qw0) {
#pragma unroll
                for (int j = 0; j < 16; ++j) {
                    int roff = (j & 3) + 8 * (j >> 2) + 4 * hi;
                    if (kv0 + roff > q) st[j] = -3e38f;
                }
            }
#pragma unroll
            for (int j = 0; j < 16; ++j) st[j] = exp_fast(st[j]);
            bf16x8 pa = packfrag(st, 0);
            bf16x8 pb = packfrag(st, 8);
            __builtin_amdgcn_s_setprio(1);
            ls = __builtin_amdgcn_mfma_f32_32x32x16_bf16(ones, pa, ls, 0, 0, 0);
            ls = __builtin_amdgcn_mfma_f32_32x32x16_bf16(ones, pb, ls, 0, 0, 0);
            o0 = __builtin_amdgcn_mfma_f32_32x32x16_bf16(*(const bf16x8*)(VB + 0 * 512), pa, o0, 0, 0, 0);
            o1 = __builtin_amdgcn_mfma_f32_32x32x16_bf16(*(const bf16x8*)(VB + 4 * 512), pa, o1, 0, 0, 0);
            o0 = __builtin_amdgcn_mfma_f32_32x32x16_bf16(*(const bf16x8*)(VB + 1 * 512), pb, o0, 0, 0, 0);
            o1 = __builtin_amdgcn_mfma_f32_32x32x16_bf16(*(const bf16x8*)(VB + 5 * 512), pb, o1, 0, 0, 0);
            __builtin_amdgcn_s_setprio(0);
        }

        // ---- half 1: kv rows [kv0+32, kv0+64) ----
        if (kv0 < qw0) {
            __builtin_amdgcn_s_setprio(1);
            f32x16 st = __builtin_amdgcn_mfma_f32_32x32x16_bf16(kf[4], qf[0], z16, 0, 0, 0);
#pragma unroll
            for (int s = 1; s < 4; ++s)
                st = __builtin_amdgcn_mfma_f32_32x32x16_bf16(kf[4 + s], qf[s], st, 0, 0, 0);
            __builtin_amdgcn_s_setprio(0);
            if (kv0 + 63 > qw0) {
#pragma unroll
                for (int j = 0; j < 16; ++j) {
                    int roff = (j & 3) + 8 * (j >> 2) + 4 * hi;
                    if (kv0 + 32 + roff > q) st[j] = -3e38f;
                }
            }
#pragma unroll
            for (int j = 0; j < 16; ++j) st[j] = exp_fast(st[j]);
            bf16x8 pa = packfrag(st, 0);
            bf16x8 pb = packfrag(st, 8);
            __builtin_amdgcn_s_setprio(1);
            ls = __builtin_amdgcn_mfma_f32_32x32x16_bf16(ones, pa, ls, 0, 0, 0);
            ls = __builtin_amdgcn_mfma_f32_32x32x16_bf16(ones, pb, ls, 0, 0, 0);
            o0 = __builtin_amdgcn_mfma_f32_32x32x16_bf16(*(const bf16x8*)(VB + 2 * 512), pa, o0, 0, 0, 0);
            o1 = __builtin_amdgcn_mfma_f32_32x32x16_bf16(*(const bf16x8*)(VB + 6 * 512), pa, o1, 0, 0, 0);
            o0 = __builtin_amdgcn_mfma_f32_32x32x16_bf16(*(const bf16x8*)(VB + 3 * 512), pb, o0, 0, 0, 0);
            o1 = __builtin_amdgcn_mfma_f32_32x32x16_bf16(*(const bf16x8*)(VB + 7 * 512), pb, o1, 0, 0, 0);
            __builtin_amdgcn_s_setprio(0);
        }
    };

    bf16x8 kfA[8], kfB[8];
    loadK(0, kfA);
    stage(0, 0);
    __syncthreads();
    for (int t = 0; t < nt; t += 2) {
        const int kv0 = t * 64;
        stage(1, kv0 + 64);
        if (kv0 + 64 < qw0 + 32) loadK(kv0 + 64, kfB);   // prefetch odd tile's K
        compute(0, kv0, kfA);
        __syncthreads();
        if (t + 2 < nt) {
            stage(0, kv0 + 128);
            if (kv0 + 128 < qw0 + 32) loadK(kv0 + 128, kfA);  // prefetch next even tile's K
        }
        compute(1, kv0 + 64, kfB);
        __syncthreads();
    }

    // ---- epilogue: every element of ls equals this lane's column sum ----
    float inv = 1.f / ls[0];
    size_t sq = (size_t)q0 + w * 32 + l31;
    unsigned short* crow = ctx + ((size_t)b * S_LEN + sq) * DMODEL + h * HDIM;
#pragma unroll
    for (int quad = 0; quad < 4; ++quad) {
        int hdbase = quad * 8 + hi * 4;
        unsigned w0 = cvt_pk_bf16(o0[4 * quad] * inv, o0[4 * quad + 1] * inv);
        unsigned w1 = cvt_pk_bf16(o0[4 * quad + 2] * inv, o0[4 * quad + 3] * inv);
        *(unsigned long long*)(crow + hdbase) = ((unsigned long long)w1 << 32) | w0;
        unsigned w2 = cvt_pk_bf16(o1[4 * quad] * inv, o1[4 * quad + 1] * inv);
        unsigned w3 = cvt_pk_bf16(o1[4 * quad + 2] * inv, o1[4 * quad + 3] * inv);
        *(unsigned long long*)(crow + 32 + hdbase) = ((unsigned long long)w3 << 32) | w2;
    }
}

extern "C" void kernel_launch(void* const* d_in, const int* in_sizes, int n_in,
                              void* d_out, int out_size, void* d_ws, size_t ws_size,
                              hipStream_t stream) {
    (void)in_sizes; (void)n_in; (void)out_size; (void)ws_size;
    const float* x  = (const float*)d_in[0];
    const float* Wq = (const float*)d_in[1];
    const float* Wk = (const float*)d_in[2];
    const float* Wv = (const float*)d_in[3];
    const float* Wo = (const float*)d_in[4];
    const float* bo = (const float*)d_in[5];

    unsigned short* ws  = (unsigned short*)d_ws;
    const size_t NTOK = (size_t)NBATCH * S_LEN;          // 8192
    unsigned short* xb  = ws;                            // [8192,1024] bf16
    unsigned short* wqb = xb  + NTOK * DMODEL;           // [1024,1024] x4 contiguous
    unsigned short* wkb = wqb + (size_t)DMODEL * DMODEL;
    unsigned short* wvb = wkb + (size_t)DMODEL * DMODEL;
    unsigned short* wob = wvb + (size_t)DMODEL * DMODEL;
    unsigned short* Qb  = wob + (size_t)DMODEL * DMODEL; // [B,H,S,64]
    unsigned short* Kb  = Qb  + NTOK * DMODEL;           // [B,H,S,64]
    unsigned short* Vt  = Kb  + NTOK * DMODEL;           // [B,H,64,S]
    unsigned short* ctx = xb;                            // reuse xb after projections

    int n4x = (int)(NTOK * DMODEL / 4);
    cvt_x<<<(n4x + 255) / 256, 256, 0, stream>>>(x, xb, n4x);
    cvt_w<<<dim3(DMODEL * DMODEL / 4 / 256, 4), 256, 0, stream>>>(Wq, Wk, Wv, Wo, wqb);

    const float qscale = 0.125f * LOG2E;
    gemm_qkv<<<dim3(64, 8, 3), 256, 0, stream>>>(xb, wqb, wkb, wvb, Qb, Kb, Vt, qscale);

    attn_fwd<<<1024, 256, 0, stream>>>(Qb, Kb, Vt, ctx);

    gemm_out<<<dim3(64, 8), 256, 0, stream>>>(ctx, wob, (float*)d_out, bo);
}

// Round 12
// 206.727 us; speedup vs baseline: 1.2245x; 1.2245x over previous
//
#include <hip/hip_runtime.h>
#include <stdint.h>
#include <stddef.h>

#define S_LEN 4096
#define NHEAD 16
#define HDIM 64
#define DMODEL 1024
#define NBATCH 2
#define LOG2E 1.4426950408889634f

typedef __attribute__((ext_vector_type(8))) short bf16x8;
typedef __attribute__((ext_vector_type(4))) float f32x4;
typedef __attribute__((ext_vector_type(16))) float f32x16;
typedef __attribute__((ext_vector_type(2))) unsigned int uint2v;
typedef __attribute__((ext_vector_type(4))) unsigned int uint4v;

__device__ inline unsigned short f2b(float f) {
    union { float f; unsigned int u; } x; x.f = f;
    unsigned int r = (x.u + 0x7fffu + ((x.u >> 16) & 1u)) >> 16;
    return (unsigned short)r;
}

__device__ inline unsigned cvt_pk_bf16(float lo, float hi) {
    unsigned r;
    asm("v_cvt_pk_bf16_f32 %0, %1, %2" : "=v"(r) : "v"(lo), "v"(hi));
    return r;
}

__device__ inline float exp_fast(float x) {  // 2^x, single v_exp_f32 (pre-scaled by log2e)
    float r;
    asm("v_exp_f32 %0, %1" : "=v"(r) : "v"(x));
    return r;
}

__device__ inline void gload_lds16(const void* g, void* l) {
    __builtin_amdgcn_global_load_lds((const __attribute__((address_space(1))) void*)g,
                                     (__attribute__((address_space(3))) void*)l,
                                     16, 0, 0);
}

// ---------------- fp32 -> bf16 converts ----------------
__global__ void cvt_x(const float* __restrict__ in, unsigned short* __restrict__ out, int n4) {
    int i = blockIdx.x * 256 + threadIdx.x;
    if (i >= n4) return;
    float4 v = ((const float4*)in)[i];
    ushort4 o;
    o.x = f2b(v.x); o.y = f2b(v.y); o.z = f2b(v.z); o.w = f2b(v.w);
    ((ushort4*)out)[i] = o;
}

__global__ void cvt_w(const float* __restrict__ w0, const float* __restrict__ w1,
                      const float* __restrict__ w2, const float* __restrict__ w3,
                      unsigned short* __restrict__ dst) {
    int z = blockIdx.y;
    const float* src = (z == 0) ? w0 : (z == 1) ? w1 : (z == 2) ? w2 : w3;
    int i = blockIdx.x * 256 + threadIdx.x;
    float4 v = ((const float4*)src)[i];
    ushort4 o;
    o.x = f2b(v.x); o.y = f2b(v.y); o.z = f2b(v.z); o.w = f2b(v.w);
    ((ushort4*)(dst + (size_t)z * DMODEL * DMODEL))[i] = o;
}

// ---------------- fused QKV projection ----------------
// z=0: Q -> [B,H,S,64] (scaled). z=1: K -> FRAGMENT-ORDER Kf[bh][t64][half][s][lane][8].
// z=2: V^T -> [B,H,64,S].
__global__ __launch_bounds__(256, 2)
void gemm_qkv(const unsigned short* __restrict__ xb,
              const unsigned short* __restrict__ wqb,
              const unsigned short* __restrict__ wkb,
              const unsigned short* __restrict__ wvb,
              unsigned short* __restrict__ Qb,
              unsigned short* __restrict__ Kf,
              unsigned short* __restrict__ Vt,
              float qscale) {
    __shared__ unsigned short Asl[128 * 64];
    __shared__ unsigned short Bsl[128 * 64];
    const int tid  = threadIdx.x;
    const int lane = tid & 63;
    const int wid  = tid >> 6;
    const int wm   = (wid >> 1) * 64, wn = (wid & 1) * 64;
    const int lr   = lane & 15, lk = lane >> 4;
    const int z    = blockIdx.z;

    const unsigned short* A;
    const unsigned short* Bw;
    int m0, n0;
    if (z < 2) { A = xb; Bw = z ? wkb : wqb; m0 = blockIdx.x * 128; n0 = blockIdx.y * 128; }
    else       { A = wvb; Bw = xb;           m0 = blockIdx.y * 128; n0 = blockIdx.x * 128; }

    f32x4 acc[4][4];
#pragma unroll
    for (int i = 0; i < 4; ++i)
#pragma unroll
        for (int j = 0; j < 4; ++j) acc[i][j] = (f32x4){0.f, 0.f, 0.f, 0.f};

    for (int kt = 0; kt < DMODEL; kt += 64) {
#pragma unroll
        for (int i = 0; i < 4; ++i) {
            int c = i * 256 + tid;
            int r = c >> 3, gc = (c & 7) ^ (r & 7);
            gload_lds16(A + (size_t)(m0 + r) * DMODEL + kt + gc * 8, Asl + c * 8);
        }
#pragma unroll
        for (int i = 0; i < 4; ++i) {
            int c = i * 256 + tid;
            int r = c >> 3, gc = (c & 7) ^ (r & 7);
            gload_lds16(Bw + (size_t)(n0 + r) * DMODEL + kt + gc * 8, Bsl + c * 8);
        }
        __syncthreads();
#pragma unroll
        for (int kh = 0; kh < 2; ++kh) {
            int cl = kh * 4 + lk;
            bf16x8 af[4], bfr[4];
#pragma unroll
            for (int m = 0; m < 4; ++m) {
                int r = wm + m * 16 + lr;
                af[m] = *(const bf16x8*)(Asl + r * 64 + ((cl ^ (r & 7)) * 8));
            }
#pragma unroll
            for (int n = 0; n < 4; ++n) {
                int r = wn + n * 16 + lr;
                bfr[n] = *(const bf16x8*)(Bsl + r * 64 + ((cl ^ (r & 7)) * 8));
            }
#pragma unroll
            for (int m = 0; m < 4; ++m)
#pragma unroll
                for (int n = 0; n < 4; ++n)
                    acc[m][n] = __builtin_amdgcn_mfma_f32_16x16x32_bf16(af[m], bfr[n], acc[m][n], 0, 0, 0);
        }
        __syncthreads();
    }

#pragma unroll
    for (int m = 0; m < 4; ++m) {
#pragma unroll
        for (int n = 0; n < 4; ++n) {
            int gn = n0 + wn + n * 16 + lr;
#pragma unroll
            for (int r = 0; r < 4; ++r) {
                int gm = m0 + wm + m * 16 + lk * 4 + r;
                float v = acc[m][n][r];
                if (z == 0) {
                    int b = gm >> 12, s = gm & 4095, h = gn >> 6, hd = gn & 63;
                    Qb[((size_t)((b * NHEAD + h) * S_LEN + s)) * HDIM + hd] = f2b(v * qscale);
                } else if (z == 1) {
                    // fragment-order K: [bh][t64][half][s-slice][lane=hi*32+l31][elem]
                    int b = gm >> 12, kv = gm & 4095, h = gn >> 6, hd = gn & 63;
                    int bh = b * NHEAD + h;
                    int t64 = kv >> 6, half = (kv >> 5) & 1, l31k = kv & 31;
                    int s = hd >> 4, hik = (hd >> 3) & 1, e = hd & 7;
                    size_t idx = (((((size_t)bh * 64 + t64) * 2 + half) * 4 + s) * 64
                                  + (hik * 32 + l31k)) * 8 + e;
                    Kf[idx] = f2b(v);
                } else {
                    int h = gm >> 6, hd = gm & 63, b = gn >> 12, s = gn & 4095;
                    Vt[((size_t)((b * NHEAD + h) * HDIM + hd)) * S_LEN + s] = f2b(v);
                }
            }
        }
    }
}

// ---------------- output projection: fp32 out + bias ----------------
__global__ __launch_bounds__(256, 2)
void gemm_out(const unsigned short* __restrict__ A,
              const unsigned short* __restrict__ Bw,
              float* __restrict__ out, const float* __restrict__ bias) {
    __shared__ unsigned short Asl[128 * 64];
    __shared__ unsigned short Bsl[128 * 64];
    const int tid  = threadIdx.x;
    const int lane = tid & 63;
    const int wid  = tid >> 6;
    const int wm   = (wid >> 1) * 64, wn = (wid & 1) * 64;
    const int lr   = lane & 15, lk = lane >> 4;
    const int m0   = blockIdx.x * 128, n0 = blockIdx.y * 128;

    f32x4 acc[4][4];
#pragma unroll
    for (int i = 0; i < 4; ++i)
#pragma unroll
        for (int j = 0; j < 4; ++j) acc[i][j] = (f32x4){0.f, 0.f, 0.f, 0.f};

    for (int kt = 0; kt < DMODEL; kt += 64) {
#pragma unroll
        for (int i = 0; i < 4; ++i) {
            int c = i * 256 + tid;
            int r = c >> 3, gc = (c & 7) ^ (r & 7);
            gload_lds16(A + (size_t)(m0 + r) * DMODEL + kt + gc * 8, Asl + c * 8);
        }
#pragma unroll
        for (int i = 0; i < 4; ++i) {
            int c = i * 256 + tid;
            int r = c >> 3, gc = (c & 7) ^ (r & 7);
            gload_lds16(Bw + (size_t)(n0 + r) * DMODEL + kt + gc * 8, Bsl + c * 8);
        }
        __syncthreads();
#pragma unroll
        for (int kh = 0; kh < 2; ++kh) {
            int cl = kh * 4 + lk;
            bf16x8 af[4], bfr[4];
#pragma unroll
            for (int m = 0; m < 4; ++m) {
                int r = wm + m * 16 + lr;
                af[m] = *(const bf16x8*)(Asl + r * 64 + ((cl ^ (r & 7)) * 8));
            }
#pragma unroll
            for (int n = 0; n < 4; ++n) {
                int r = wn + n * 16 + lr;
                bfr[n] = *(const bf16x8*)(Bsl + r * 64 + ((cl ^ (r & 7)) * 8));
            }
#pragma unroll
            for (int m = 0; m < 4; ++m)
#pragma unroll
                for (int n = 0; n < 4; ++n)
                    acc[m][n] = __builtin_amdgcn_mfma_f32_16x16x32_bf16(af[m], bfr[n], acc[m][n], 0, 0, 0);
        }
        __syncthreads();
    }
#pragma unroll
    for (int m = 0; m < 4; ++m)
#pragma unroll
        for (int n = 0; n < 4; ++n) {
            int gn = n0 + wn + n * 16 + lr;
#pragma unroll
            for (int r = 0; r < 4; ++r) {
                int gm = m0 + wm + m * 16 + lk * 4 + r;
                out[(size_t)gm * DMODEL + gn] = acc[m][n][r] + bias[gn];
            }
        }
}

// ---------------- flash attention (causal): fragment-order K from L2, V in LDS ----
// K fragments load coalesced (base + lane*16) from Kf; no K LDS, no K barrier.
// V double-buffered in LDS (16 KB). Per 64-kv tile: 8 ds_read + 2 stage-gloads
// (was 16 + 4) -> LDS pressure and barrier drain halved.
__global__ __launch_bounds__(256)
void attn_fwd(const unsigned short* __restrict__ Q,
              const unsigned short* __restrict__ Kf,
              const unsigned short* __restrict__ Vt,
              unsigned short* __restrict__ ctx) {
    __shared__ unsigned short Vl[2][4096];

    const int tid  = threadIdx.x;
    const int lane = tid & 63;
    const int w    = tid >> 6;
    const int l31  = lane & 31;
    const int hi   = lane >> 5;

    // balanced mapping (r10): per-CU qt sums equal under round-robin dispatch
    const int bid  = blockIdx.x;
    const int xcd  = bid & 7;
    const int cu   = (bid >> 3) & 31;
    const int slot = bid >> 8;
    const int u    = cu >> 2;
    int qt;
    if      (slot == 0) qt = 31 - u;
    else if (slot == 1) qt = 16 + u;
    else if (slot == 2) qt = 15 - u;
    else                qt = u;
    const int bh   = (xcd << 2) | (cu & 3);          // 4 heads per XCD (L2 locality)
    const int b    = bh >> 4, h = bh & 15;
    const int q0   = qt * 128;
    const int qw0  = q0 + w * 32;

    const unsigned short* Qh  = Q  + (size_t)bh * S_LEN * HDIM;
    const unsigned short* Kfh = Kf + (size_t)bh * 64 * 2 * 2048;  // [t64][half][4][64][8]
    const unsigned short* Vh  = Vt + (size_t)bh * HDIM * S_LEN;

    // V staging source (fragment-order): slice sk = tid>>6
    const int sk   = tid >> 6;
    const int lS31 = tid & 31, hiS = (tid >> 5) & 1;
    const unsigned short* vb0 = Vh + (size_t)lS31 * S_LEN + sk * 16 + hiS * 8;
    const unsigned short* vb1 = Vh + (size_t)(32 + lS31) * S_LEN + sk * 16 + hiS * 8;

    // Q fragments (B-operand): col q = lane&31, k-elems hd = s*16 + hi*8 + 0..7
    bf16x8 qf[4];
    {
        const unsigned short* qrow = Qh + (size_t)(qw0 + l31) * HDIM + hi * 8;
#pragma unroll
        for (int s = 0; s < 4; ++s) qf[s] = *(const bf16x8*)(qrow + s * 16);
    }

    bf16x8 ones;
#pragma unroll
    for (int j = 0; j < 8; ++j) ones[j] = (short)0x3F80;

    f32x16 z16;
#pragma unroll
    for (int j = 0; j < 16; ++j) z16[j] = 0.f;

    const unsigned short* VL = &Vl[0][0] + lane * 8;
    const unsigned short* KFL = Kfh + lane * 8;      // + (t64*2+half)*2048 + s*512

    f32x16 o0, o1, ls;
#pragma unroll
    for (int j = 0; j < 16; ++j) { o0[j] = 0.f; o1[j] = 0.f; ls[j] = 0.f; }

    const int nt = 2 * qt + 2;             // always even

    auto stage = [&](int buf, int kv0) {
        gload_lds16(vb0 + kv0, &Vl[buf][(size_t)tid * 8]);
        gload_lds16(vb1 + kv0, &Vl[buf][2048 + (size_t)tid * 8]);
    };

    auto packfrag = [&](const f32x16& v, int base) -> bf16x8 {
        unsigned a0 = cvt_pk_bf16(v[base + 0], v[base + 1]), a1 = cvt_pk_bf16(v[base + 2], v[base + 3]);
        unsigned b0 = cvt_pk_bf16(v[base + 4], v[base + 5]), b1 = cvt_pk_bf16(v[base + 6], v[base + 7]);
        uint2v r0 = __builtin_amdgcn_permlane32_swap(a0, b0, false, false);
        uint2v r1 = __builtin_amdgcn_permlane32_swap(a1, b1, false, false);
        uint4v f; f.x = r0.x; f.y = r1.x; f.z = r0.y; f.w = r1.y;
        return __builtin_bit_cast(bf16x8, f);
    };

    auto compute = [&](int buf, int kv0) {
        const unsigned short* VB = VL + buf * 4096;
        const int q = qw0 + l31;

        // ---- half 0: kv rows [kv0, kv0+32) ----
        if (kv0 < qw0 + 32) {
            const unsigned short* kb = KFL + ((size_t)(kv0 >> 6) * 2 + 0) * 2048;
            bf16x8 k0 = *(const bf16x8*)(kb + 0 * 512);
            bf16x8 k1 = *(const bf16x8*)(kb + 1 * 512);
            bf16x8 k2 = *(const bf16x8*)(kb + 2 * 512);
            bf16x8 k3 = *(const bf16x8*)(kb + 3 * 512);
            __builtin_amdgcn_s_setprio(1);
            f32x16 st = __builtin_amdgcn_mfma_f32_32x32x16_bf16(k0, qf[0], z16, 0, 0, 0);
            st = __builtin_amdgcn_mfma_f32_32x32x16_bf16(k1, qf[1], st, 0, 0, 0);
            st = __builtin_amdgcn_mfma_f32_32x32x16_bf16(k2, qf[2], st, 0, 0, 0);
            st = __builtin_amdgcn_mfma_f32_32x32x16_bf16(k3, qf[3], st, 0, 0, 0);
            __builtin_amdgcn_s_setprio(0);
            if (kv0 + 31 > qw0) {
#pragma unroll
                for (int j = 0; j < 16; ++j) {
                    int roff = (j & 3) + 8 * (j >> 2) + 4 * hi;
                    if (kv0 + roff > q) st[j] = -3e38f;
                }
            }
#pragma unroll
            for (int j = 0; j < 16; ++j) st[j] = exp_fast(st[j]);
            bf16x8 pa = packfrag(st, 0);
            bf16x8 pb = packfrag(st, 8);
            __builtin_amdgcn_s_setprio(1);
            ls = __builtin_amdgcn_mfma_f32_32x32x16_bf16(ones, pa, ls, 0, 0, 0);
            ls = __builtin_amdgcn_mfma_f32_32x32x16_bf16(ones, pb, ls, 0, 0, 0);
            o0 = __builtin_amdgcn_mfma_f32_32x32x16_bf16(*(const bf16x8*)(VB + 0 * 512), pa, o0, 0, 0, 0);
            o1 = __builtin_amdgcn_mfma_f32_32x32x16_bf16(*(const bf16x8*)(VB + 4 * 512), pa, o1, 0, 0, 0);
            o0 = __builtin_amdgcn_mfma_f32_32x32x16_bf16(*(const bf16x8*)(VB + 1 * 512), pb, o0, 0, 0, 0);
            o1 = __builtin_amdgcn_mfma_f32_32x32x16_bf16(*(const bf16x8*)(VB + 5 * 512), pb, o1, 0, 0, 0);
            __builtin_amdgcn_s_setprio(0);
        }

        // ---- half 1: kv rows [kv0+32, kv0+64) ----
        if (kv0 < qw0) {
            const unsigned short* kb = KFL + ((size_t)(kv0 >> 6) * 2 + 1) * 2048;
            bf16x8 k0 = *(const bf16x8*)(kb + 0 * 512);
            bf16x8 k1 = *(const bf16x8*)(kb + 1 * 512);
            bf16x8 k2 = *(const bf16x8*)(kb + 2 * 512);
            bf16x8 k3 = *(const bf16x8*)(kb + 3 * 512);
            __builtin_amdgcn_s_setprio(1);
            f32x16 st = __builtin_amdgcn_mfma_f32_32x32x16_bf16(k0, qf[0], z16, 0, 0, 0);
            st = __builtin_amdgcn_mfma_f32_32x32x16_bf16(k1, qf[1], st, 0, 0, 0);
            st = __builtin_amdgcn_mfma_f32_32x32x16_bf16(k2, qf[2], st, 0, 0, 0);
            st = __builtin_amdgcn_mfma_f32_32x32x16_bf16(k3, qf[3], st, 0, 0, 0);
            __builtin_amdgcn_s_setprio(0);
            if (kv0 + 63 > qw0) {
#pragma unroll
                for (int j = 0; j < 16; ++j) {
                    int roff = (j & 3) + 8 * (j >> 2) + 4 * hi;
                    if (kv0 + 32 + roff > q) st[j] = -3e38f;
                }
            }
#pragma unroll
            for (int j = 0; j < 16; ++j) st[j] = exp_fast(st[j]);
            bf16x8 pa = packfrag(st, 0);
            bf16x8 pb = packfrag(st, 8);
            __builtin_amdgcn_s_setprio(1);
            ls = __builtin_amdgcn_mfma_f32_32x32x16_bf16(ones, pa, ls, 0, 0, 0);
            ls = __builtin_amdgcn_mfma_f32_32x32x16_bf16(ones, pb, ls, 0, 0, 0);
            o0 = __builtin_amdgcn_mfma_f32_32x32x16_bf16(*(const bf16x8*)(VB + 2 * 512), pa, o0, 0, 0, 0);
            o1 = __builtin_amdgcn_mfma_f32_32x32x16_bf16(*(const bf16x8*)(VB + 6 * 512), pa, o1, 0, 0, 0);
            o0 = __builtin_amdgcn_mfma_f32_32x32x16_bf16(*(const bf16x8*)(VB + 3 * 512), pb, o0, 0, 0, 0);
            o1 = __builtin_amdgcn_mfma_f32_32x32x16_bf16(*(const bf16x8*)(VB + 7 * 512), pb, o1, 0, 0, 0);
            __builtin_amdgcn_s_setprio(0);
        }
    };

    stage(0, 0);
    __syncthreads();
    for (int t = 0; t < nt; t += 2) {
        const int kv0 = t * 64;
        stage(1, kv0 + 64);
        compute(0, kv0);
        __syncthreads();
        if (t + 2 < nt) stage(0, kv0 + 128);
        compute(1, kv0 + 64);
        __syncthreads();
    }

    // ---- epilogue: every element of ls equals this lane's column sum ----
    float inv = 1.f / ls[0];
    size_t sq = (size_t)q0 + w * 32 + l31;
    unsigned short* crow = ctx + ((size_t)b * S_LEN + sq) * DMODEL + h * HDIM;
#pragma unroll
    for (int quad = 0; quad < 4; ++quad) {
        int hdbase = quad * 8 + hi * 4;
        unsigned w0 = cvt_pk_bf16(o0[4 * quad] * inv, o0[4 * quad + 1] * inv);
        unsigned w1 = cvt_pk_bf16(o0[4 * quad + 2] * inv, o0[4 * quad + 3] * inv);
        *(unsigned long long*)(crow + hdbase) = ((unsigned long long)w1 << 32) | w0;
        unsigned w2 = cvt_pk_bf16(o1[4 * quad] * inv, o1[4 * quad + 1] * inv);
        unsigned w3 = cvt_pk_bf16(o1[4 * quad + 2] * inv, o1[4 * quad + 3] * inv);
        *(unsigned long long*)(crow + 32 + hdbase) = ((unsigned long long)w3 << 32) | w2;
    }
}

extern "C" void kernel_launch(void* const* d_in, const int* in_sizes, int n_in,
                              void* d_out, int out_size, void* d_ws, size_t ws_size,
                              hipStream_t stream) {
    (void)in_sizes; (void)n_in; (void)out_size; (void)ws_size;
    const float* x  = (const float*)d_in[0];
    const float* Wq = (const float*)d_in[1];
    const float* Wk = (const float*)d_in[2];
    const float* Wv = (const float*)d_in[3];
    const float* Wo = (const float*)d_in[4];
    const float* bo = (const float*)d_in[5];

    unsigned short* ws  = (unsigned short*)d_ws;
    const size_t NTOK = (size_t)NBATCH * S_LEN;          // 8192
    unsigned short* xb  = ws;                            // [8192,1024] bf16
    unsigned short* wqb = xb  + NTOK * DMODEL;           // [1024,1024] x4 contiguous
    unsigned short* wkb = wqb + (size_t)DMODEL * DMODEL;
    unsigned short* wvb = wkb + (size_t)DMODEL * DMODEL;
    unsigned short* wob = wvb + (size_t)DMODEL * DMODEL;
    unsigned short* Qb  = wob + (size_t)DMODEL * DMODEL; // [B,H,S,64]
    unsigned short* Kfr = Qb  + NTOK * DMODEL;           // fragment-order K, 16 MB
    unsigned short* Vt  = Kfr + NTOK * DMODEL;           // [B,H,64,S]
    unsigned short* ctx = xb;                            // reuse xb after projections

    int n4x = (int)(NTOK * DMODEL / 4);
    cvt_x<<<(n4x + 255) / 256, 256, 0, stream>>>(x, xb, n4x);
    cvt_w<<<dim3(DMODEL * DMODEL / 4 / 256, 4), 256, 0, stream>>>(Wq, Wk, Wv, Wo, wqb);

    const float qscale = 0.125f * LOG2E;
    gemm_qkv<<<dim3(64, 8, 3), 256, 0, stream>>>(xb, wqb, wkb, wvb, Qb, Kfr, Vt, qscale);

    attn_fwd<<<1024, 256, 0, stream>>>(Qb, Kfr, Vt, ctx);

    gemm_out<<<dim3(64, 8), 256, 0, stream>>>(ctx, wob, (float*)d_out, bo);
}

// Round 13
// 191.489 us; speedup vs baseline: 1.3219x; 1.0796x over previous
//
#include <hip/hip_runtime.h>
#include <stdint.h>
#include <stddef.h>

#define S_LEN 4096
#define NHEAD 16
#define HDIM 64
#define DMODEL 1024
#define NBATCH 2
#define LOG2E 1.4426950408889634f

typedef __attribute__((ext_vector_type(8))) short bf16x8;
typedef __attribute__((ext_vector_type(4))) float f32x4;
typedef __attribute__((ext_vector_type(16))) float f32x16;
typedef __attribute__((ext_vector_type(2))) unsigned int uint2v;
typedef __attribute__((ext_vector_type(4))) unsigned int uint4v;

__device__ inline unsigned short f2b(float f) {
    union { float f; unsigned int u; } x; x.f = f;
    unsigned int r = (x.u + 0x7fffu + ((x.u >> 16) & 1u)) >> 16;
    return (unsigned short)r;
}

__device__ inline unsigned cvt_pk_bf16(float lo, float hi) {
    unsigned r;
    asm("v_cvt_pk_bf16_f32 %0, %1, %2" : "=v"(r) : "v"(lo), "v"(hi));
    return r;
}

__device__ inline float exp_fast(float x) {  // 2^x, single v_exp_f32 (pre-scaled by log2e)
    float r;
    asm("v_exp_f32 %0, %1" : "=v"(r) : "v"(x));
    return r;
}

__device__ inline void gload_lds16(const void* g, void* l) {
    __builtin_amdgcn_global_load_lds((const __attribute__((address_space(1))) void*)g,
                                     (__attribute__((address_space(3))) void*)l,
                                     16, 0, 0);
}

// ---------------- fused fp32 -> bf16 convert (x + 4 weights, one launch) ----------
// blocks [0, n4x/256) -> x; remainder -> weights (z = j>>18 selects Wq/Wk/Wv/Wo).
__global__ void cvt_all(const float* __restrict__ x,
                        const float* __restrict__ w0, const float* __restrict__ w1,
                        const float* __restrict__ w2, const float* __restrict__ w3,
                        unsigned short* __restrict__ xb,
                        unsigned short* __restrict__ wb, int n4x) {
    int i = blockIdx.x * 256 + threadIdx.x;
    const float* src;
    unsigned short* dst;
    int idx;
    if (i < n4x) {
        src = x; dst = xb; idx = i;
    } else {
        int j = i - n4x;
        int z = j >> 18;                       // 1024*1024/4 = 2^18 float4s per weight
        idx = j & 0x3FFFF;
        src = (z == 0) ? w0 : (z == 1) ? w1 : (z == 2) ? w2 : w3;
        dst = wb + (size_t)z * DMODEL * DMODEL;
    }
    float4 v = ((const float4*)src)[idx];
    ushort4 o;
    o.x = f2b(v.x); o.y = f2b(v.y); o.z = f2b(v.z); o.w = f2b(v.w);
    ((ushort4*)dst)[idx] = o;
}

// ---------------- fused QKV projection ----------------
__global__ __launch_bounds__(256, 2)
void gemm_qkv(const unsigned short* __restrict__ xb,
              const unsigned short* __restrict__ wqb,
              const unsigned short* __restrict__ wkb,
              const unsigned short* __restrict__ wvb,
              unsigned short* __restrict__ Qb,
              unsigned short* __restrict__ Kb,
              unsigned short* __restrict__ Vt,
              float qscale) {
    __shared__ unsigned short Asl[128 * 64];
    __shared__ unsigned short Bsl[128 * 64];
    const int tid  = threadIdx.x;
    const int lane = tid & 63;
    const int wid  = tid >> 6;
    const int wm   = (wid >> 1) * 64, wn = (wid & 1) * 64;
    const int lr   = lane & 15, lk = lane >> 4;
    const int z    = blockIdx.z;

    const unsigned short* A;
    const unsigned short* Bw;
    int m0, n0;
    if (z < 2) { A = xb; Bw = z ? wkb : wqb; m0 = blockIdx.x * 128; n0 = blockIdx.y * 128; }
    else       { A = wvb; Bw = xb;           m0 = blockIdx.y * 128; n0 = blockIdx.x * 128; }

    f32x4 acc[4][4];
#pragma unroll
    for (int i = 0; i < 4; ++i)
#pragma unroll
        for (int j = 0; j < 4; ++j) acc[i][j] = (f32x4){0.f, 0.f, 0.f, 0.f};

    for (int kt = 0; kt < DMODEL; kt += 64) {
#pragma unroll
        for (int i = 0; i < 4; ++i) {
            int c = i * 256 + tid;
            int r = c >> 3, gc = (c & 7) ^ (r & 7);
            gload_lds16(A + (size_t)(m0 + r) * DMODEL + kt + gc * 8, Asl + c * 8);
        }
#pragma unroll
        for (int i = 0; i < 4; ++i) {
            int c = i * 256 + tid;
            int r = c >> 3, gc = (c & 7) ^ (r & 7);
            gload_lds16(Bw + (size_t)(n0 + r) * DMODEL + kt + gc * 8, Bsl + c * 8);
        }
        __syncthreads();
#pragma unroll
        for (int kh = 0; kh < 2; ++kh) {
            int cl = kh * 4 + lk;
            bf16x8 af[4], bfr[4];
#pragma unroll
            for (int m = 0; m < 4; ++m) {
                int r = wm + m * 16 + lr;
                af[m] = *(const bf16x8*)(Asl + r * 64 + ((cl ^ (r & 7)) * 8));
            }
#pragma unroll
            for (int n = 0; n < 4; ++n) {
                int r = wn + n * 16 + lr;
                bfr[n] = *(const bf16x8*)(Bsl + r * 64 + ((cl ^ (r & 7)) * 8));
            }
#pragma unroll
            for (int m = 0; m < 4; ++m)
#pragma unroll
                for (int n = 0; n < 4; ++n)
                    acc[m][n] = __builtin_amdgcn_mfma_f32_16x16x32_bf16(af[m], bfr[n], acc[m][n], 0, 0, 0);
        }
        __syncthreads();
    }

#pragma unroll
    for (int m = 0; m < 4; ++m) {
#pragma unroll
        for (int n = 0; n < 4; ++n) {
            int gn = n0 + wn + n * 16 + lr;
#pragma unroll
            for (int r = 0; r < 4; ++r) {
                int gm = m0 + wm + m * 16 + lk * 4 + r;
                float v = acc[m][n][r];
                if (z == 0) {
                    int b = gm >> 12, s = gm & 4095, h = gn >> 6, hd = gn & 63;
                    Qb[((size_t)((b * NHEAD + h) * S_LEN + s)) * HDIM + hd] = f2b(v * qscale);
                } else if (z == 1) {
                    int b = gm >> 12, s = gm & 4095, h = gn >> 6, hd = gn & 63;
                    Kb[((size_t)((b * NHEAD + h) * S_LEN + s)) * HDIM + hd] = f2b(v);
                } else {
                    int h = gm >> 6, hd = gm & 63, b = gn >> 12, s = gn & 4095;
                    Vt[((size_t)((b * NHEAD + h) * HDIM + hd)) * S_LEN + s] = f2b(v);
                }
            }
        }
    }
}

// ---------------- output projection: fp32 out + bias ----------------
__global__ __launch_bounds__(256, 2)
void gemm_out(const unsigned short* __restrict__ A,
              const unsigned short* __restrict__ Bw,
              float* __restrict__ out, const float* __restrict__ bias) {
    __shared__ unsigned short Asl[128 * 64];
    __shared__ unsigned short Bsl[128 * 64];
    const int tid  = threadIdx.x;
    const int lane = tid & 63;
    const int wid  = tid >> 6;
    const int wm   = (wid >> 1) * 64, wn = (wid & 1) * 64;
    const int lr   = lane & 15, lk = lane >> 4;
    const int m0   = blockIdx.x * 128, n0 = blockIdx.y * 128;

    f32x4 acc[4][4];
#pragma unroll
    for (int i = 0; i < 4; ++i)
#pragma unroll
        for (int j = 0; j < 4; ++j) acc[i][j] = (f32x4){0.f, 0.f, 0.f, 0.f};

    for (int kt = 0; kt < DMODEL; kt += 64) {
#pragma unroll
        for (int i = 0; i < 4; ++i) {
            int c = i * 256 + tid;
            int r = c >> 3, gc = (c & 7) ^ (r & 7);
            gload_lds16(A + (size_t)(m0 + r) * DMODEL + kt + gc * 8, Asl + c * 8);
        }
#pragma unroll
        for (int i = 0; i < 4; ++i) {
            int c = i * 256 + tid;
            int r = c >> 3, gc = (c & 7) ^ (r & 7);
            gload_lds16(Bw + (size_t)(n0 + r) * DMODEL + kt + gc * 8, Bsl + c * 8);
        }
        __syncthreads();
#pragma unroll
        for (int kh = 0; kh < 2; ++kh) {
            int cl = kh * 4 + lk;
            bf16x8 af[4], bfr[4];
#pragma unroll
            for (int m = 0; m < 4; ++m) {
                int r = wm + m * 16 + lr;
                af[m] = *(const bf16x8*)(Asl + r * 64 + ((cl ^ (r & 7)) * 8));
            }
#pragma unroll
            for (int n = 0; n < 4; ++n) {
                int r = wn + n * 16 + lr;
                bfr[n] = *(const bf16x8*)(Bsl + r * 64 + ((cl ^ (r & 7)) * 8));
            }
#pragma unroll
            for (int m = 0; m < 4; ++m)
#pragma unroll
                for (int n = 0; n < 4; ++n)
                    acc[m][n] = __builtin_amdgcn_mfma_f32_16x16x32_bf16(af[m], bfr[n], acc[m][n], 0, 0, 0);
        }
        __syncthreads();
    }
#pragma unroll
    for (int m = 0; m < 4; ++m)
#pragma unroll
        for (int n = 0; n < 4; ++n) {
            int gn = n0 + wn + n * 16 + lr;
#pragma unroll
            for (int r = 0; r < 4; ++r) {
                int gm = m0 + wm + m * 16 + lk * 4 + r;
                out[(size_t)gm * DMODEL + gn] = acc[m][n][r] + bias[gn];
            }
        }
}

// ---------------- flash attention (causal), no-max softmax + ones-MFMA row sums ----
// Round-6 structure (best measured): raw v_exp_f32 + zero-C-operand init + XCD head
// grouping + heavy-tiles-first. KVBLK=64 double-buffer, fragment-order LDS.
__global__ __launch_bounds__(256)
void attn_fwd(const unsigned short* __restrict__ Q,
              const unsigned short* __restrict__ K,
              const unsigned short* __restrict__ Vt,
              unsigned short* __restrict__ ctx) {
    __shared__ unsigned short Kl[2][4096];
    __shared__ unsigned short Vl[2][4096];

    const int tid  = threadIdx.x;
    const int lane = tid & 63;
    const int w    = tid >> 6;
    const int l31  = lane & 31;
    const int hi   = lane >> 5;

    // XCD grouping: each XCD (bid&7) owns 4 heads -> K+V working set = 4MB = one L2.
    const int bid  = blockIdx.x;
    const int qt   = 31 - (bid >> 5);                       // heavy q-tiles first
    const int bh   = ((bid & 7) << 2) | ((bid >> 3) & 3);   // bijective over 0..31
    const int b    = bh >> 4, h = bh & 15;
    const int q0   = qt * 128;
    const int qw0  = q0 + w * 32;

    const unsigned short* Qh = Q  + (size_t)bh * S_LEN * HDIM;
    const unsigned short* Kh = K  + (size_t)bh * S_LEN * HDIM;
    const unsigned short* Vh = Vt + (size_t)bh * HDIM * S_LEN;

    // staging source bases (fragment-order)
    const int skA  = tid >> 6;
    const int lS   = tid & 63;
    const int lS31 = lS & 31, hiS = lS >> 5;
    const unsigned short* kb0 = Kh + (size_t)lS31 * HDIM + skA * 16 + hiS * 8;
    const unsigned short* kb1 = Kh + (size_t)(32 + lS31) * HDIM + skA * 16 + hiS * 8;
    const unsigned short* vb0 = Vh + (size_t)lS31 * S_LEN + skA * 16 + hiS * 8;
    const unsigned short* vb1 = Vh + (size_t)(32 + lS31) * S_LEN + skA * 16 + hiS * 8;

    // Q fragments (B-operand): col q = lane&31, k-elems hd = s*16 + hi*8 + 0..7
    bf16x8 qf[4];
    {
        const unsigned short* qrow = Qh + (size_t)(qw0 + l31) * HDIM + hi * 8;
#pragma unroll
        for (int s = 0; s < 4; ++s) qf[s] = *(const bf16x8*)(qrow + s * 16);
    }

    // all-ones A-operand fragment for row-sum MFMA
    bf16x8 ones;
#pragma unroll
    for (int j = 0; j < 8; ++j) ones[j] = (short)0x3F80;

    // loop-invariant zero C-operand (first QK MFMA reads it, never written)
    f32x16 z16;
#pragma unroll
    for (int j = 0; j < 16; ++j) z16[j] = 0.f;

    const unsigned short* KL = &Kl[0][0] + lane * 8;
    const unsigned short* VL = &Vl[0][0] + lane * 8;

    f32x16 o0, o1, ls;
#pragma unroll
    for (int j = 0; j < 16; ++j) { o0[j] = 0.f; o1[j] = 0.f; ls[j] = 0.f; }

    const int nt = 2 * qt + 2;             // always even

    auto stage = [&](int buf, int kv0) {
        gload_lds16(kb0 + (size_t)kv0 * HDIM, &Kl[buf][(size_t)tid * 8]);
        gload_lds16(kb1 + (size_t)kv0 * HDIM, &Kl[buf][2048 + (size_t)tid * 8]);
        gload_lds16(vb0 + kv0, &Vl[buf][(size_t)tid * 8]);
        gload_lds16(vb1 + kv0, &Vl[buf][2048 + (size_t)tid * 8]);
    };

    auto packfrag = [&](const f32x16& v, int base) -> bf16x8 {
        unsigned a0 = cvt_pk_bf16(v[base + 0], v[base + 1]), a1 = cvt_pk_bf16(v[base + 2], v[base + 3]);
        unsigned b0 = cvt_pk_bf16(v[base + 4], v[base + 5]), b1 = cvt_pk_bf16(v[base + 6], v[base + 7]);
        uint2v r0 = __builtin_amdgcn_permlane32_swap(a0, b0, false, false);
        uint2v r1 = __builtin_amdgcn_permlane32_swap(a1, b1, false, false);
        uint4v f; f.x = r0.x; f.y = r1.x; f.z = r0.y; f.w = r1.y;
        return __builtin_bit_cast(bf16x8, f);
    };

    auto compute = [&](int buf, int kv0) {
        const unsigned short* KB = KL + buf * 4096;
        const unsigned short* VB = VL + buf * 4096;
        const int q = qw0 + l31;

        // ---- half 0: kv rows [kv0, kv0+32) ----
        if (kv0 < qw0 + 32) {
            __builtin_amdgcn_s_setprio(1);
            f32x16 st = __builtin_amdgcn_mfma_f32_32x32x16_bf16(
                            *(const bf16x8*)(KB + 0 * 512), qf[0], z16, 0, 0, 0);
#pragma unroll
            for (int s = 1; s < 4; ++s)
                st = __builtin_amdgcn_mfma_f32_32x32x16_bf16(
                        *(const bf16x8*)(KB + s * 512), qf[s], st, 0, 0, 0);
            __builtin_amdgcn_s_setprio(0);
            if (kv0 + 31 > qw0) {
#pragma unroll
                for (int j = 0; j < 16; ++j) {
                    int roff = (j & 3) + 8 * (j >> 2) + 4 * hi;
                    if (kv0 + roff > q) st[j] = -3e38f;
                }
            }
#pragma unroll
            for (int j = 0; j < 16; ++j) st[j] = exp_fast(st[j]);
            bf16x8 pa = packfrag(st, 0);
            bf16x8 pb = packfrag(st, 8);
            __builtin_amdgcn_s_setprio(1);
            ls = __builtin_amdgcn_mfma_f32_32x32x16_bf16(ones, pa, ls, 0, 0, 0);
            ls = __builtin_amdgcn_mfma_f32_32x32x16_bf16(ones, pb, ls, 0, 0, 0);
            o0 = __builtin_amdgcn_mfma_f32_32x32x16_bf16(*(const bf16x8*)(VB + 0 * 512), pa, o0, 0, 0, 0);
            o1 = __builtin_amdgcn_mfma_f32_32x32x16_bf16(*(const bf16x8*)(VB + 4 * 512), pa, o1, 0, 0, 0);
            o0 = __builtin_amdgcn_mfma_f32_32x32x16_bf16(*(const bf16x8*)(VB + 1 * 512), pb, o0, 0, 0, 0);
            o1 = __builtin_amdgcn_mfma_f32_32x32x16_bf16(*(const bf16x8*)(VB + 5 * 512), pb, o1, 0, 0, 0);
            __builtin_amdgcn_s_setprio(0);
        }

        // ---- half 1: kv rows [kv0+32, kv0+64) ----
        if (kv0 < qw0) {
            __builtin_amdgcn_s_setprio(1);
            f32x16 st = __builtin_amdgcn_mfma_f32_32x32x16_bf16(
                            *(const bf16x8*)(KB + 4 * 512), qf[0], z16, 0, 0, 0);
#pragma unroll
            for (int s = 1; s < 4; ++s)
                st = __builtin_amdgcn_mfma_f32_32x32x16_bf16(
                        *(const bf16x8*)(KB + (4 + s) * 512), qf[s], st, 0, 0, 0);
            __builtin_amdgcn_s_setprio(0);
            if (kv0 + 63 > qw0) {
#pragma unroll
                for (int j = 0; j < 16; ++j) {
                    int roff = (j & 3) + 8 * (j >> 2) + 4 * hi;
                    if (kv0 + 32 + roff > q) st[j] = -3e38f;
                }
            }
#pragma unroll
            for (int j = 0; j < 16; ++j) st[j] = exp_fast(st[j]);
            bf16x8 pa = packfrag(st, 0);
            bf16x8 pb = packfrag(st, 8);
            __builtin_amdgcn_s_setprio(1);
            ls = __builtin_amdgcn_mfma_f32_32x32x16_bf16(ones, pa, ls, 0, 0, 0);
            ls = __builtin_amdgcn_mfma_f32_32x32x16_bf16(ones, pb, ls, 0, 0, 0);
            o0 = __builtin_amdgcn_mfma_f32_32x32x16_bf16(*(const bf16x8*)(VB + 2 * 512), pa, o0, 0, 0, 0);
            o1 = __builtin_amdgcn_mfma_f32_32x32x16_bf16(*(const bf16x8*)(VB + 6 * 512), pa, o1, 0, 0, 0);
            o0 = __builtin_amdgcn_mfma_f32_32x32x16_bf16(*(const bf16x8*)(VB + 3 * 512), pb, o0, 0, 0, 0);
            o1 = __builtin_amdgcn_mfma_f32_32x32x16_bf16(*(const bf16x8*)(VB + 7 * 512), pb, o1, 0, 0, 0);
            __builtin_amdgcn_s_setprio(0);
        }
    };

    stage(0, 0);
    __syncthreads();
    for (int t = 0; t < nt; t += 2) {
        const int kv0 = t * 64;
        stage(1, kv0 + 64);
        compute(0, kv0);
        __syncthreads();
        if (t + 2 < nt) stage(0, kv0 + 128);
        compute(1, kv0 + 64);
        __syncthreads();
    }

    // ---- epilogue: every element of ls equals this lane's column sum ----
    float inv = 1.f / ls[0];
    size_t sq = (size_t)q0 + w * 32 + l31;
    unsigned short* crow = ctx + ((size_t)b * S_LEN + sq) * DMODEL + h * HDIM;
#pragma unroll
    for (int quad = 0; quad < 4; ++quad) {
        int hdbase = quad * 8 + hi * 4;
        unsigned w0 = cvt_pk_bf16(o0[4 * quad] * inv, o0[4 * quad + 1] * inv);
        unsigned w1 = cvt_pk_bf16(o0[4 * quad + 2] * inv, o0[4 * quad + 3] * inv);
        *(unsigned long long*)(crow + hdbase) = ((unsigned long long)w1 << 32) | w0;
        unsigned w2 = cvt_pk_bf16(o1[4 * quad] * inv, o1[4 * quad + 1] * inv);
        unsigned w3 = cvt_pk_bf16(o1[4 * quad + 2] * inv, o1[4 * quad + 3] * inv);
        *(unsigned long long*)(crow + 32 + hdbase) = ((unsigned long long)w3 << 32) | w2;
    }
}

extern "C" void kernel_launch(void* const* d_in, const int* in_sizes, int n_in,
                              void* d_out, int out_size, void* d_ws, size_t ws_size,
                              hipStream_t stream) {
    (void)in_sizes; (void)n_in; (void)out_size; (void)ws_size;
    const float* x  = (const float*)d_in[0];
    const float* Wq = (const float*)d_in[1];
    const float* Wk = (const float*)d_in[2];
    const float* Wv = (const float*)d_in[3];
    const float* Wo = (const float*)d_in[4];
    const float* bo = (const float*)d_in[5];

    unsigned short* ws  = (unsigned short*)d_ws;
    const size_t NTOK = (size_t)NBATCH * S_LEN;          // 8192
    unsigned short* xb  = ws;                            // [8192,1024] bf16
    unsigned short* wqb = xb  + NTOK * DMODEL;           // [1024,1024] x4 contiguous
    unsigned short* wkb = wqb + (size_t)DMODEL * DMODEL;
    unsigned short* wvb = wkb + (size_t)DMODEL * DMODEL;
    unsigned short* wob = wvb + (size_t)DMODEL * DMODEL;
    unsigned short* Qb  = wob + (size_t)DMODEL * DMODEL; // [B,H,S,64]
    unsigned short* Kb  = Qb  + NTOK * DMODEL;           // [B,H,S,64]
    unsigned short* Vt  = Kb  + NTOK * DMODEL;           // [B,H,64,S]
    unsigned short* ctx = xb;                            // reuse xb after projections

    int n4x = (int)(NTOK * DMODEL / 4);                  // 2,097,152 float4s
    int n4w = 4 * DMODEL * DMODEL / 4;                   // 1,048,576 float4s
    cvt_all<<<(n4x + n4w) / 256, 256, 0, stream>>>(x, Wq, Wk, Wv, Wo, xb, wqb, n4x);

    const float qscale = 0.125f * LOG2E;
    gemm_qkv<<<dim3(64, 8, 3), 256, 0, stream>>>(xb, wqb, wkb, wvb, Qb, Kb, Vt, qscale);

    attn_fwd<<<1024, 256, 0, stream>>>(Qb, Kb, Vt, ctx);

    gemm_out<<<dim3(64, 8), 256, 0, stream>>>(ctx, wob, (float*)d_out, bo);
}